// Round 16
// baseline (113.368 us; speedup 1.0000x reference)
//
#include <hip/hip_runtime.h>
#include <math.h>

#define Hh 512
#define Ww 512
#define Bb 4
#define Ee 32
#define PLANE (Hh*Ww)        // 262144
#define NOFF 9
#define EC 16                // e-planes per block (2 e-chunks)
#define BUFF 3584            // floats per LDS buffer: T rows h-3..h+3 (7*512)

// ws layout (float indices)
#define WS_BLUR   0
#define WS_MIN    524304
#define WS_MAX    524320
#define WS_ACC    524336
#define WS_CNT    524338

__device__ __constant__ int d_OH[NOFF] = {0,-1,-1,0,-2,-2,0,-3,-3};
__device__ __constant__ int d_OW[NOFF] = {-1,0,-1,-2,0,-2,-3,0,-3};

__device__ __forceinline__ void gload_lds16(const float* g, float* l){
    __builtin_amdgcn_global_load_lds(
        (const __attribute__((address_space(1))) void*)g,
        (__attribute__((address_space(3))) void*)l, 16, 0, 0);
}

#define WAITV(n) asm volatile("s_waitcnt vmcnt(" #n ")" ::: "memory")
#define SCB()    __builtin_amdgcn_sched_barrier(0)
#define RBAR()   __builtin_amdgcn_s_barrier()

// ---- fused 2D gaussian blur (sigma=1.2, r=5, edge-clamped), 32x32 tiles + halo
#define TS 32
#define HALO 5
__global__ __launch_bounds__(256) void k_blur(const float* __restrict__ raw,
                                              float* __restrict__ ws){
    __shared__ float sraw[TS+2*HALO][TS+2*HALO+1];
    __shared__ float shb [TS][TS+2*HALO+1];
    int tx = blockIdx.x & 15, ty = blockIdx.x >> 4;
    int r0 = ty*TS - HALO, c0 = tx*TS - HALO;

    double kd[11], s = 0.0;
    #pragma unroll
    for (int i = 0; i < 11; i++){
        double x = (double)(i - 5) / 1.2;
        kd[i] = exp(-0.5 * x * x);
        s += kd[i];
    }
    float w[11];
    #pragma unroll
    for (int i = 0; i < 11; i++) w[i] = (float)(kd[i] / s);

    for (int t = threadIdx.x; t < 42*42; t += 256){
        int rr = t / 42, cc = t - rr*42;
        int gr = min(max(r0+rr, 0), Hh-1);
        int gc = min(max(c0+cc, 0), Ww-1);
        sraw[rr][cc] = raw[gr*Ww + gc];
    }
    __syncthreads();
    for (int t = threadIdx.x; t < TS*42; t += 256){
        int rr = t / 42, cc = t - rr*42;
        float a = 0.f;
        #pragma unroll
        for (int i = 0; i < 11; i++) a += w[i] * sraw[rr+i][cc];
        shb[rr][cc] = a;
    }
    __syncthreads();
    for (int t = threadIdx.x; t < TS*TS; t += 256){
        int rr = t >> 5, cc = t & 31;
        float a = 0.f;
        #pragma unroll
        for (int i = 0; i < 11; i++) a += w[i] * shb[rr][cc+i];
        ws[WS_BLUR + (ty*TS+rr)*Ww + (tx*TS+cc)] = a;
    }
    if (blockIdx.x == 0){
        if (threadIdx.x < 16){
            ((unsigned int*)(ws + WS_MIN))[threadIdx.x] = 0x7F800000u;
            ((unsigned int*)(ws + WS_MAX))[threadIdx.x] = 0u;
        }
        if (threadIdx.x == 0){
            *(double*)(ws + WS_ACC) = 0.0;
            *(unsigned int*)(ws + WS_CNT) = 0u;
        }
    }
}

// per-offset min/max of d_i = |blur - rolled blur|
__global__ void k_minmax(float* __restrict__ ws){
    int idx = blockIdx.x * 512 + threadIdx.x;
    int h = idx >> 9, w = idx & 511;
    float bc = ws[WS_BLUR + idx];
    int lane = threadIdx.x & 63, wv = threadIdx.x >> 6;
    __shared__ float smn[8 * NOFF], smx[8 * NOFF];
    #pragma unroll
    for (int i = 0; i < NOFF; i++){
        int hn = (h + d_OH[i]) & (Hh-1);
        int wn = (w + d_OW[i]) & (Ww-1);
        float d = fabsf(bc - ws[WS_BLUR + hn * Ww + wn]);
        float mnv = d, mxv = d;
        for (int s = 32; s; s >>= 1){
            mnv = fminf(mnv, __shfl_xor(mnv, s));
            mxv = fmaxf(mxv, __shfl_xor(mxv, s));
        }
        if (lane == 0){ smn[wv * NOFF + i] = mnv; smx[wv * NOFF + i] = mxv; }
    }
    __syncthreads();
    if (threadIdx.x < NOFF){
        float mnv = smn[threadIdx.x], mxv = smx[threadIdx.x];
        for (int v = 1; v < 8; v++){
            mnv = fminf(mnv, smn[v * NOFF + threadIdx.x]);
            mxv = fmaxf(mxv, smx[v * NOFF + threadIdx.x]);
        }
        atomicMin((unsigned int*)(ws + WS_MIN) + threadIdx.x, __float_as_uint(mnv));
        atomicMax((unsigned int*)(ws + WS_MAX) + threadIdx.x, __float_as_uint(mxv));
    }
}

// fused loss: 512-thr block = 4 rows x 512 cols, EC=16 e-planes (2 e-chunks).
// grid = 4 batches x 2 e-chunks x 128 rowgroups = 1024 (4 blocks/CU queued).
// T staged in LDS: 4 buffers x 14KB = 57.3KB — combined with grid>=4/CU this
// is the proven co-residency recipe (R12: 42% occ; R13 same LDS at grid 512
// stayed at 21%). E double-buffered in two named regs (R13-verified). Counted
// vmcnt (never 0 in-loop), single raw s_barrier per plane. csum once (csw).
__global__ __launch_bounds__(512)
void k_main(const float* __restrict__ E, const float* __restrict__ T,
            const float* __restrict__ mask, float* __restrict__ ws,
            float* __restrict__ out){
    __shared__ float sL[4*BUFF];
    __shared__ float sp[8];

    int blk = blockIdx.x;             // 0..1023
    int bb  = blk >> 8;               // batch
    int ec  = (blk >> 7) & 1;         // e-chunk
    int rg  = blk & 127;              // rowgroup
    int row4 = rg << 2;
    int e0  = ec << 4;

    int tid = threadIdx.x;
    int rq  = tid >> 7;               // 0..3
    int wq  = tid & 127;
    int wv  = tid >> 6;               // wave 0..7
    int ln  = tid & 63;
    int hr  = row4 + rq;
    int c0  = wq << 2;
    int cl  = (c0 - 4) & 511;
    int pix = hr * Ww + c0;

    // ---- per-pixel coefficients c[j][i] from blurred raw + mask (prologue vmem)
    const float* bl = ws + WS_BLUR;
    float tb[4][8];
    #pragma unroll
    for (int r = 0; r < 4; r++){
        int rr = (hr - r) & 511;
        float4 l4 = *(const float4*)(bl + rr*Ww + cl);
        float4 o4 = *(const float4*)(bl + rr*Ww + c0);
        tb[r][0]=l4.x; tb[r][1]=l4.y; tb[r][2]=l4.z; tb[r][3]=l4.w;
        tb[r][4]=o4.x; tb[r][5]=o4.y; tb[r][6]=o4.z; tb[r][7]=o4.w;
    }
    const unsigned int* mnb = (const unsigned int*)(ws + WS_MIN);
    const unsigned int* mxb = (const unsigned int*)(ws + WS_MAX);
    float mn[NOFF], inv[NOFF];
    #pragma unroll
    for (int i = 0; i < NOFF; i++){
        mn[i]  = __uint_as_float(mnb[i]);
        inv[i] = 1.f / (__uint_as_float(mxb[i]) - mn[i]);
    }
    float c[4][NOFF];
    float acc[4];
    float csw = (ec == 0) ? 1.f : 0.f;   // csum exactly once per pixel
    #pragma unroll
    for (int j = 0; j < 4; j++){
        float bc = tb[0][4+j];
        float d[NOFF];
        d[0] = fabsf(bc - tb[0][3+j]);
        d[1] = fabsf(bc - tb[1][4+j]);
        d[2] = fabsf(bc - tb[1][3+j]);
        d[3] = fabsf(bc - tb[0][2+j]);
        d[4] = fabsf(bc - tb[2][4+j]);
        d[5] = fabsf(bc - tb[2][2+j]);
        d[6] = fabsf(bc - tb[0][1+j]);
        d[7] = fabsf(bc - tb[3][4+j]);
        d[8] = fabsf(bc - tb[3][1+j]);
        acc[j] = 0.f;
        #pragma unroll
        for (int i = 0; i < NOFF; i++){
            float a = (d[i] - mn[i]) * inv[i];
            float mv = ((const float*)(mask + i * PLANE + pix))[j];
            c[j][i] = mv * (0.5f - a);
            acc[j] = fmaf(csw, c[j][i], acc[j]);
        }
    }

    // ---- per-wave T staging chunks: wv stages chunk wv, and wv+8 if wv<6
    const float* Tbase = T + (size_t)bb * Ee * PLANE + (size_t)e0 * PLANE;
    const float* Eb    = E + (size_t)bb * Ee * PLANE + (size_t)e0 * PLANE + pix;
    const float* gp0; const float* gp1 = 0;
    int lo0, lo1 = 0;
    {
        int r0c = wv >> 1, h0 = (wv & 1) << 8;
        gp0 = Tbase + ((row4 - 3 + r0c) & 511)*Ww + h0 + ln*4;
        lo0 = r0c*512 + h0 + ln*4;
        if (wv < 6){
            int r1c = (wv >> 1) + 4;
            gp1 = Tbase + ((row4 - 3 + r1c) & 511)*Ww + h0 + ln*4;
            lo1 = r1c*512 + h0 + ln*4;
        }
    }

    #define STG(bi, k) do { \
        size_t ko = (size_t)(k) * PLANE; \
        float* lb = sL + (bi)*BUFF; \
        gload_lds16(gp0 + ko, lb + lo0); \
        if (wv < 6) gload_lds16(gp1 + ko, lb + lo1); \
    } while(0)

    #define CMPB(bi, EV) do { \
        const float* tT = sL + (bi)*BUFF; \
        float s0, s1, s2, s3; \
        { const float* rp = tT + (3 + rq) * 512; \
          float4 l4 = *(const float4*)(rp + cl); \
          float4 o4 = *(const float4*)(rp + c0); \
          float t[8] = {l4.x,l4.y,l4.z,l4.w, o4.x,o4.y,o4.z,o4.w}; \
          s0 = c[0][0]*t[3]; s0 = fmaf(c[0][3], t[2], s0); s0 = fmaf(c[0][6], t[1], s0); \
          s1 = c[1][0]*t[4]; s1 = fmaf(c[1][3], t[3], s1); s1 = fmaf(c[1][6], t[2], s1); \
          s2 = c[2][0]*t[5]; s2 = fmaf(c[2][3], t[4], s2); s2 = fmaf(c[2][6], t[3], s2); \
          s3 = c[3][0]*t[6]; s3 = fmaf(c[3][3], t[5], s3); s3 = fmaf(c[3][6], t[4], s3); } \
        { const float* rp = tT + (2 + rq) * 512; \
          float4 l4 = *(const float4*)(rp + cl); \
          float4 o4 = *(const float4*)(rp + c0); \
          float t[8] = {l4.x,l4.y,l4.z,l4.w, o4.x,o4.y,o4.z,o4.w}; \
          s0 = fmaf(c[0][1], t[4], s0); s0 = fmaf(c[0][2], t[3], s0); \
          s1 = fmaf(c[1][1], t[5], s1); s1 = fmaf(c[1][2], t[4], s1); \
          s2 = fmaf(c[2][1], t[6], s2); s2 = fmaf(c[2][2], t[5], s2); \
          s3 = fmaf(c[3][1], t[7], s3); s3 = fmaf(c[3][2], t[6], s3); } \
        { const float* rp = tT + (1 + rq) * 512; \
          float4 l4 = *(const float4*)(rp + cl); \
          float4 o4 = *(const float4*)(rp + c0); \
          float t[8] = {l4.x,l4.y,l4.z,l4.w, o4.x,o4.y,o4.z,o4.w}; \
          s0 = fmaf(c[0][4], t[4], s0); s0 = fmaf(c[0][5], t[2], s0); \
          s1 = fmaf(c[1][4], t[5], s1); s1 = fmaf(c[1][5], t[3], s1); \
          s2 = fmaf(c[2][4], t[6], s2); s2 = fmaf(c[2][5], t[4], s2); \
          s3 = fmaf(c[3][4], t[7], s3); s3 = fmaf(c[3][5], t[5], s3); } \
        { const float* rp = tT + (0 + rq) * 512; \
          float4 l4 = *(const float4*)(rp + cl); \
          float4 o4 = *(const float4*)(rp + c0); \
          float t[8] = {l4.x,l4.y,l4.z,l4.w, o4.x,o4.y,o4.z,o4.w}; \
          s0 = fmaf(c[0][7], t[4], s0); s0 = fmaf(c[0][8], t[1], s0); \
          s1 = fmaf(c[1][7], t[5], s1); s1 = fmaf(c[1][8], t[2], s1); \
          s2 = fmaf(c[2][7], t[6], s2); s2 = fmaf(c[2][8], t[3], s2); \
          s3 = fmaf(c[3][7], t[7], s3); s3 = fmaf(c[3][8], t[4], s3); } \
        acc[0] = fmaf(-(EV).x, s0, acc[0]); \
        acc[1] = fmaf(-(EV).y, s1, acc[1]); \
        acc[2] = fmaf(-(EV).z, s2, acc[2]); \
        acc[3] = fmaf(-(EV).w, s3, acc[3]); \
    } while(0)

    // E planes 0,1 into regs (prologue; drained below, so vmcnt stays clean)
    float4 eva = *(const float4*)(Eb);
    float4 evb = *(const float4*)(Eb + (size_t)PLANE);

    // drain ALL prologue vmem so vmcnt counts only pipeline loads
    WAITV(0); SCB();

    // depth-2 prologue
    STG(0, 0);
    STG(1, 1);

    // steady state: plane k consumes STG(k)+eva; prefetch STG(k+2), E(k+2).
    // Outstanding at WAITV: {E(k),STG(k+1),E(k+1),STG(k+2)} -> keep 6 / 4.
    #pragma unroll 1
    for (int k = 0; k < EC-4; k += 2){
        STG((k + 2) & 3, k + 2);
        if (wv < 6) { WAITV(6); } else { WAITV(4); }
        SCB(); RBAR(); SCB();
        CMPB(k & 3, eva);
        SCB();
        eva = *(const float4*)(Eb + (size_t)(k + 2) * PLANE);
        SCB();
        STG((k + 3) & 3, k + 3);
        if (wv < 6) { WAITV(6); } else { WAITV(4); }
        SCB(); RBAR(); SCB();
        CMPB((k + 1) & 3, evb);
        SCB();
        evb = *(const float4*)(Eb + (size_t)(k + 3) * PLANE);
        SCB();
    }
    // plane EC-4: stage EC-2, compute EC-4, load E(EC-2)
    STG((EC-2) & 3, EC-2);
    if (wv < 6) { WAITV(6); } else { WAITV(4); }
    SCB(); RBAR(); SCB();
    CMPB((EC-4) & 3, eva);
    SCB();
    eva = *(const float4*)(Eb + (size_t)(EC-2) * PLANE);
    SCB();
    // plane EC-3: stage EC-1, compute EC-3, load E(EC-1)
    STG((EC-1) & 3, EC-1);
    if (wv < 6) { WAITV(6); } else { WAITV(4); }
    SCB(); RBAR(); SCB();
    CMPB((EC-3) & 3, evb);
    SCB();
    evb = *(const float4*)(Eb + (size_t)(EC-1) * PLANE);
    SCB();
    // plane EC-2: outstanding {E(EC-2), STG(EC-1), E(EC-1)} -> keep 4 / 3
    if (wv < 6) { WAITV(4); } else { WAITV(3); }
    SCB(); RBAR(); SCB();
    CMPB((EC-2) & 3, eva);
    // plane EC-1: drain
    WAITV(0);
    SCB(); RBAR(); SCB();
    CMPB((EC-1) & 3, evb);

    float part = acc[0] + acc[1] + acc[2] + acc[3];
    for (int s = 32; s; s >>= 1) part += __shfl_xor(part, s);
    if (ln == 0) sp[wv] = part;
    __syncthreads();
    if (tid == 0){
        float bs = 0.f;
        #pragma unroll
        for (int v = 0; v < 8; v++) bs += sp[v];
        double* accp = (double*)(ws + WS_ACC);
        atomicAdd(accp, (double)bs);
        __threadfence();
        unsigned int done = atomicAdd((unsigned int*)(ws + WS_CNT), 1u);
        if (done == gridDim.x - 1){
            double v = atomicAdd(accp, 0.0);
            out[0] = (float)(v / (double)((size_t)Bb * PLANE));
        }
    }
}

extern "C" void kernel_launch(void* const* d_in, const int* in_sizes, int n_in,
                              void* d_out, int out_size, void* d_ws, size_t ws_size,
                              hipStream_t stream) {
    const float* embeds = (const float*)d_in[0];   // [4,32,512,512]
    const float* tf     = (const float*)d_in[1];   // [4,32,512,512]
    const float* raw    = (const float*)d_in[2];   // [1,1,512,512]
    const float* mask   = (const float*)d_in[3];   // [1,9,512,512]
    float* ws  = (float*)d_ws;
    float* out = (float*)d_out;

    k_blur  <<<256, 256, 0, stream>>>(raw, ws);
    k_minmax<<<PLANE/512, 512, 0, stream>>>(ws);
    k_main  <<<1024, 512, 0, stream>>>(embeds, tf, mask, ws, out);
}

// Round 17
// 88.706 us; speedup vs baseline: 1.2780x; 1.2780x over previous
//
#include <hip/hip_runtime.h>
#include <math.h>

#define Hh 512
#define Ww 512
#define Bb 4
#define Ee 32
#define PLANE (Hh*Ww)        // 262144
#define NOFF 9
#define BUFF 5632            // floats per LDS buffer: T 7*512 + E 4*512

// ws layout (float indices)
#define WS_BLUR   0
#define WS_MIN    524304
#define WS_MAX    524320
#define WS_ACC    524336
#define WS_CNT    524338

__device__ __constant__ int d_OH[NOFF] = {0,-1,-1,0,-2,-2,0,-3,-3};
__device__ __constant__ int d_OW[NOFF] = {-1,0,-1,-2,0,-2,-3,0,-3};

__device__ __forceinline__ void gload_lds16(const float* g, float* l){
    __builtin_amdgcn_global_load_lds(
        (const __attribute__((address_space(1))) void*)g,
        (__attribute__((address_space(3))) void*)l, 16, 0, 0);
}

#define WAITV(n) asm volatile("s_waitcnt vmcnt(" #n ")" ::: "memory")
#define SCB()    __builtin_amdgcn_sched_barrier(0)
#define RBAR()   __builtin_amdgcn_s_barrier()

// ---- fused 2D gaussian blur (sigma=1.2, r=5, edge-clamped), 32x32 tiles + halo
#define TS 32
#define HALO 5
__global__ __launch_bounds__(256) void k_blur(const float* __restrict__ raw,
                                              float* __restrict__ ws){
    __shared__ float sraw[TS+2*HALO][TS+2*HALO+1];
    __shared__ float shb [TS][TS+2*HALO+1];
    int tx = blockIdx.x & 15, ty = blockIdx.x >> 4;
    int r0 = ty*TS - HALO, c0 = tx*TS - HALO;

    double kd[11], s = 0.0;
    #pragma unroll
    for (int i = 0; i < 11; i++){
        double x = (double)(i - 5) / 1.2;
        kd[i] = exp(-0.5 * x * x);
        s += kd[i];
    }
    float w[11];
    #pragma unroll
    for (int i = 0; i < 11; i++) w[i] = (float)(kd[i] / s);

    for (int t = threadIdx.x; t < 42*42; t += 256){
        int rr = t / 42, cc = t - rr*42;
        int gr = min(max(r0+rr, 0), Hh-1);
        int gc = min(max(c0+cc, 0), Ww-1);
        sraw[rr][cc] = raw[gr*Ww + gc];
    }
    __syncthreads();
    for (int t = threadIdx.x; t < TS*42; t += 256){
        int rr = t / 42, cc = t - rr*42;
        float a = 0.f;
        #pragma unroll
        for (int i = 0; i < 11; i++) a += w[i] * sraw[rr+i][cc];
        shb[rr][cc] = a;
    }
    __syncthreads();
    for (int t = threadIdx.x; t < TS*TS; t += 256){
        int rr = t >> 5, cc = t & 31;
        float a = 0.f;
        #pragma unroll
        for (int i = 0; i < 11; i++) a += w[i] * shb[rr][cc+i];
        ws[WS_BLUR + (ty*TS+rr)*Ww + (tx*TS+cc)] = a;
    }
    if (blockIdx.x == 0){
        if (threadIdx.x < 16){
            ((unsigned int*)(ws + WS_MIN))[threadIdx.x] = 0x7F800000u;
            ((unsigned int*)(ws + WS_MAX))[threadIdx.x] = 0u;
        }
        if (threadIdx.x == 0){
            *(double*)(ws + WS_ACC) = 0.0;
            *(unsigned int*)(ws + WS_CNT) = 0u;
        }
    }
}

// per-offset min/max of d_i = |blur - rolled blur|
__global__ void k_minmax(float* __restrict__ ws){
    int idx = blockIdx.x * 512 + threadIdx.x;
    int h = idx >> 9, w = idx & 511;
    float bc = ws[WS_BLUR + idx];
    int lane = threadIdx.x & 63, wv = threadIdx.x >> 6;
    __shared__ float smn[8 * NOFF], smx[8 * NOFF];
    #pragma unroll
    for (int i = 0; i < NOFF; i++){
        int hn = (h + d_OH[i]) & (Hh-1);
        int wn = (w + d_OW[i]) & (Ww-1);
        float d = fabsf(bc - ws[WS_BLUR + hn * Ww + wn]);
        float mnv = d, mxv = d;
        for (int s = 32; s; s >>= 1){
            mnv = fminf(mnv, __shfl_xor(mnv, s));
            mxv = fmaxf(mxv, __shfl_xor(mxv, s));
        }
        if (lane == 0){ smn[wv * NOFF + i] = mnv; smx[wv * NOFF + i] = mxv; }
    }
    __syncthreads();
    if (threadIdx.x < NOFF){
        float mnv = smn[threadIdx.x], mxv = smx[threadIdx.x];
        for (int v = 1; v < 8; v++){
            mnv = fminf(mnv, smn[v * NOFF + threadIdx.x]);
            mxv = fmaxf(mxv, smx[v * NOFF + threadIdx.x]);
        }
        atomicMin((unsigned int*)(ws + WS_MIN) + threadIdx.x, __float_as_uint(mnv));
        atomicMax((unsigned int*)(ws + WS_MAX) + threadIdx.x, __float_as_uint(mxv));
    }
}

// fused loss: 512-thr block = 4 rows x 512 cols of one batch, all 32 e-planes.
// LDS pipeline: 4 buffers, depth-2 prefetch, counted vmcnt + raw s_barrier.
// Per plane: 22 gload_lds chunks (T rows h-3..h+3: 14, E rows h..h+3: 8).
// This is the best verified configuration (R9, 89.3us): R10 (2nd barrier),
// R13 (E-in-reg), R14 (depth-3), R15 (2 blocks/CU) all neutral-to-worse.
__global__ __launch_bounds__(512)
void k_main(const float* __restrict__ E, const float* __restrict__ T,
            const float* __restrict__ mask, float* __restrict__ ws,
            float* __restrict__ out){
    __shared__ float sL[4*BUFF];
    __shared__ float sp[8];

    int blk = blockIdx.x;             // 0..511
    int bb  = blk >> 7;               // batch
    int rg  = blk & 127;
    int row4 = rg << 2;

    int tid = threadIdx.x;
    int rq  = tid >> 7;               // 0..3
    int wq  = tid & 127;
    int wv  = tid >> 6;               // wave 0..7
    int ln  = tid & 63;
    int hr  = row4 + rq;
    int c0  = wq << 2;
    int cl  = (c0 - 4) & 511;
    int pix = hr * Ww + c0;

    // ---- per-pixel coefficients c[j][i] from blurred raw + mask (prologue vmem)
    const float* bl = ws + WS_BLUR;
    float tb[4][8];
    #pragma unroll
    for (int r = 0; r < 4; r++){
        int rr = (hr - r) & 511;
        float4 l4 = *(const float4*)(bl + rr*Ww + cl);
        float4 o4 = *(const float4*)(bl + rr*Ww + c0);
        tb[r][0]=l4.x; tb[r][1]=l4.y; tb[r][2]=l4.z; tb[r][3]=l4.w;
        tb[r][4]=o4.x; tb[r][5]=o4.y; tb[r][6]=o4.z; tb[r][7]=o4.w;
    }
    const unsigned int* mnb = (const unsigned int*)(ws + WS_MIN);
    const unsigned int* mxb = (const unsigned int*)(ws + WS_MAX);
    float mn[NOFF], inv[NOFF];
    #pragma unroll
    for (int i = 0; i < NOFF; i++){
        mn[i]  = __uint_as_float(mnb[i]);
        inv[i] = 1.f / (__uint_as_float(mxb[i]) - mn[i]);
    }
    float c[4][NOFF];
    float acc[4];
    #pragma unroll
    for (int j = 0; j < 4; j++){
        float bc = tb[0][4+j];
        float d[NOFF];
        d[0] = fabsf(bc - tb[0][3+j]);
        d[1] = fabsf(bc - tb[1][4+j]);
        d[2] = fabsf(bc - tb[1][3+j]);
        d[3] = fabsf(bc - tb[0][2+j]);
        d[4] = fabsf(bc - tb[2][4+j]);
        d[5] = fabsf(bc - tb[2][2+j]);
        d[6] = fabsf(bc - tb[0][1+j]);
        d[7] = fabsf(bc - tb[3][4+j]);
        d[8] = fabsf(bc - tb[3][1+j]);
        acc[j] = 0.f;
        #pragma unroll
        for (int i = 0; i < NOFF; i++){
            float a = (d[i] - mn[i]) * inv[i];
            float mv = ((const float*)(mask + i * PLANE + pix))[j];
            c[j][i] = mv * (0.5f - a);
            acc[j] += c[j][i];
        }
    }

    // ---- per-wave staging chunk setup: chunks {wv, wv+8, wv+16(if wv<6)}
    const float* Tbase = T + (size_t)bb * Ee * PLANE;
    const float* Ebase = E + (size_t)bb * Ee * PLANE;
    const float* gp0; const float* gp1; const float* gp2 = 0;
    int lo0, lo1, lo2 = 0;
    {
        int ch0 = wv, ch1 = wv + 8, ch2 = wv + 16;
        {
            int r = ch0 >> 1, hf = (ch0 & 1) << 8;
            gp0 = Tbase + ((row4 - 3 + r) & 511)*Ww + hf + ln*4;
            lo0 = r*512 + hf + ln*4;
        }
        if (ch1 < 14){
            int r = ch1 >> 1, hf = (ch1 & 1) << 8;
            gp1 = Tbase + ((row4 - 3 + r) & 511)*Ww + hf + ln*4;
            lo1 = r*512 + hf + ln*4;
        } else {
            int t2 = ch1 - 14, r = t2 >> 1, hf = (t2 & 1) << 8;
            gp1 = Ebase + (row4 + r)*Ww + hf + ln*4;
            lo1 = 7*512 + r*512 + hf + ln*4;
        }
        if (wv < 6){
            int t2 = ch2 - 14, r = t2 >> 1, hf = (t2 & 1) << 8;
            gp2 = Ebase + (row4 + r)*Ww + hf + ln*4;
            lo2 = 7*512 + r*512 + hf + ln*4;
        }
    }

    #define STG(bi, k) do { \
        size_t ko = (size_t)(k) * PLANE; \
        float* lb = sL + (bi)*BUFF; \
        gload_lds16(gp0 + ko, lb + lo0); \
        gload_lds16(gp1 + ko, lb + lo1); \
        if (wv < 6) gload_lds16(gp2 + ko, lb + lo2); \
    } while(0)

    #define CMPB(bi) do { \
        const float* tT = sL + (bi)*BUFF; \
        const float* tE = tT + 7*512; \
        float4 ev4 = *(const float4*)(tE + rq*512 + c0); \
        float s0, s1, s2, s3; \
        { const float* rp = tT + (3 + rq) * 512; \
          float4 l4 = *(const float4*)(rp + cl); \
          float4 o4 = *(const float4*)(rp + c0); \
          float t[8] = {l4.x,l4.y,l4.z,l4.w, o4.x,o4.y,o4.z,o4.w}; \
          s0 = c[0][0]*t[3]; s0 = fmaf(c[0][3], t[2], s0); s0 = fmaf(c[0][6], t[1], s0); \
          s1 = c[1][0]*t[4]; s1 = fmaf(c[1][3], t[3], s1); s1 = fmaf(c[1][6], t[2], s1); \
          s2 = c[2][0]*t[5]; s2 = fmaf(c[2][3], t[4], s2); s2 = fmaf(c[2][6], t[3], s2); \
          s3 = c[3][0]*t[6]; s3 = fmaf(c[3][3], t[5], s3); s3 = fmaf(c[3][6], t[4], s3); } \
        { const float* rp = tT + (2 + rq) * 512; \
          float4 l4 = *(const float4*)(rp + cl); \
          float4 o4 = *(const float4*)(rp + c0); \
          float t[8] = {l4.x,l4.y,l4.z,l4.w, o4.x,o4.y,o4.z,o4.w}; \
          s0 = fmaf(c[0][1], t[4], s0); s0 = fmaf(c[0][2], t[3], s0); \
          s1 = fmaf(c[1][1], t[5], s1); s1 = fmaf(c[1][2], t[4], s1); \
          s2 = fmaf(c[2][1], t[6], s2); s2 = fmaf(c[2][2], t[5], s2); \
          s3 = fmaf(c[3][1], t[7], s3); s3 = fmaf(c[3][2], t[6], s3); } \
        { const float* rp = tT + (1 + rq) * 512; \
          float4 l4 = *(const float4*)(rp + cl); \
          float4 o4 = *(const float4*)(rp + c0); \
          float t[8] = {l4.x,l4.y,l4.z,l4.w, o4.x,o4.y,o4.z,o4.w}; \
          s0 = fmaf(c[0][4], t[4], s0); s0 = fmaf(c[0][5], t[2], s0); \
          s1 = fmaf(c[1][4], t[5], s1); s1 = fmaf(c[1][5], t[3], s1); \
          s2 = fmaf(c[2][4], t[6], s2); s2 = fmaf(c[2][5], t[4], s2); \
          s3 = fmaf(c[3][4], t[7], s3); s3 = fmaf(c[3][5], t[5], s3); } \
        { const float* rp = tT + (0 + rq) * 512; \
          float4 l4 = *(const float4*)(rp + cl); \
          float4 o4 = *(const float4*)(rp + c0); \
          float t[8] = {l4.x,l4.y,l4.z,l4.w, o4.x,o4.y,o4.z,o4.w}; \
          s0 = fmaf(c[0][7], t[4], s0); s0 = fmaf(c[0][8], t[1], s0); \
          s1 = fmaf(c[1][7], t[5], s1); s1 = fmaf(c[1][8], t[2], s1); \
          s2 = fmaf(c[2][7], t[6], s2); s2 = fmaf(c[2][8], t[3], s2); \
          s3 = fmaf(c[3][7], t[7], s3); s3 = fmaf(c[3][8], t[4], s3); } \
        acc[0] = fmaf(-ev4.x, s0, acc[0]); \
        acc[1] = fmaf(-ev4.y, s1, acc[1]); \
        acc[2] = fmaf(-ev4.z, s2, acc[2]); \
        acc[3] = fmaf(-ev4.w, s3, acc[3]); \
    } while(0)

    // drain all prologue vmem so vmcnt counts only staging loads
    WAITV(0); SCB();

    // depth-2 prologue
    STG(0, 0);
    STG(1, 1);

    // main loop: planes 0..29; counted waits keep 2 planes in flight
    #pragma unroll 1
    for (int k = 0; k < 30; k++){
        STG((k + 2) & 3, k + 2);
        if (wv < 6) { WAITV(6); } else { WAITV(4); }
        SCB();
        RBAR();
        SCB();
        CMPB(k & 3);
    }
    // k=30: no stage; wait own n_w (plane 31 still in flight)
    if (wv < 6) { WAITV(3); } else { WAITV(2); }
    SCB();
    RBAR();
    SCB();
    CMPB(30 & 3);
    // k=31: drain
    WAITV(0);
    SCB();
    RBAR();
    SCB();
    CMPB(31 & 3);

    float part = acc[0] + acc[1] + acc[2] + acc[3];
    for (int s = 32; s; s >>= 1) part += __shfl_xor(part, s);
    if (ln == 0) sp[wv] = part;
    __syncthreads();
    if (tid == 0){
        float bs = 0.f;
        #pragma unroll
        for (int v = 0; v < 8; v++) bs += sp[v];
        double* accp = (double*)(ws + WS_ACC);
        atomicAdd(accp, (double)bs);
        __threadfence();
        unsigned int done = atomicAdd((unsigned int*)(ws + WS_CNT), 1u);
        if (done == gridDim.x - 1){
            double v = atomicAdd(accp, 0.0);
            out[0] = (float)(v / (double)((size_t)Bb * PLANE));
        }
    }
}

extern "C" void kernel_launch(void* const* d_in, const int* in_sizes, int n_in,
                              void* d_out, int out_size, void* d_ws, size_t ws_size,
                              hipStream_t stream) {
    const float* embeds = (const float*)d_in[0];   // [4,32,512,512]
    const float* tf     = (const float*)d_in[1];   // [4,32,512,512]
    const float* raw    = (const float*)d_in[2];   // [1,1,512,512]
    const float* mask   = (const float*)d_in[3];   // [1,9,512,512]
    float* ws  = (float*)d_ws;
    float* out = (float*)d_out;

    k_blur  <<<256, 256, 0, stream>>>(raw, ws);
    k_minmax<<<PLANE/512, 512, 0, stream>>>(ws);
    k_main  <<<512, 512, 0, stream>>>(embeds, tf, mask, ws, out);
}